// Round 23
// baseline (144.769 us; speedup 1.0000x reference)
//
#include <hip/hip_runtime.h>
#include <hip/hip_bf16.h>

typedef __attribute__((ext_vector_type(8))) short short8v;   // bf16x8 fragment
typedef __attribute__((ext_vector_type(4))) float float4v;   // fp32x4 accum
typedef unsigned short ushort;
typedef unsigned int uint;

namespace {

constexpr int Hh = 192, Ww = 192, Cc = 16, Oo = 64, Bb = 4;
constexpr int TH = 4, TW = 32, NT = 128;     // 4x32 pixel tile, 128 threads (2 waves)
constexpr int HW = Hh * Ww;                  // 36864
constexpr int NPL = Bb * Cc;                 // 64 planes
constexpr int PVG_PLANE = 236 * 198;         // col-prefix plane
constexpr int PHG_PLANE = 198 * 236;         // row-prefix plane
constexpr size_t PLANE = (size_t)Bb * Oo * HW;                 // 9437184 floats
constexpr size_t PREFIX_FLOATS = (size_t)NPL * (PVG_PLANE + PHG_PLANE);
constexpr size_t WBF_FLOATS = 65536 / 2;
constexpr size_t NEED_FULL = (PREFIX_FLOATS + WBF_FLOATS + 2 * PLANE) * 4;  // 99,553,280
// prep decomposition (256-thread blocks):
constexpr int PH_ROWS  = NPL * 198;          // 12672 rows, 1 wave each
constexpr int PH_B     = PH_ROWS / 4;        // 3168 blocks (4 waves/block)
constexpr int PV_B     = (NPL * 198 + 255) / 256;   // 50 blocks
constexpr int WP_B     = 65536 / 256;        // 256 blocks
constexpr int PREP_B   = PH_B + PV_B + WP_B; // 3474

// Each feature = (vertical segment sum) + (horizontal segment sum), scaled by 1/n.
struct FD { int hasV; int vdj, vi0, vi1; int hasH; int hdi, hj0, hj1; float inv_n; };

constexpr FD FT[49] = {
    // 9 inner taps (i,j) row-major, n=1 (as V-singles)
    {1,-1,-1,-1, 0,0,0,0, 1.f}, {1, 0,-1,-1, 0,0,0,0, 1.f}, {1, 1,-1,-1, 0,0,0,0, 1.f},
    {1,-1, 0, 0, 0,0,0,0, 1.f}, {1, 0, 0, 0, 0,0,0,0, 1.f}, {1, 1, 0, 0, 0,0,0,0, 1.f},
    {1,-1, 1, 1, 0,0,0,0, 1.f}, {1, 0, 1, 1, 0,0,0,0, 1.f}, {1, 1, 1, 1, 0,0,0,0, 1.f},
    // ring5 (16)
    {1,-2,-2, 2, 1,-2,-1, 2, 1.f/9.f},
    {1,-1,-2, 2, 0,0,0,0, 0.2f},
    {1, 0,-2, 2, 0,0,0,0, 0.2f},
    {1, 1,-2, 2, 0,0,0,0, 0.2f},
    {1, 2,-2, 2, 1,-2,-2, 1, 1.f/9.f},
    {0,0,0,0, 1,-1,-2, 2, 0.2f},
    {0,0,0,0, 1,-1,-2, 2, 0.2f},
    {0,0,0,0, 1, 0,-2, 2, 0.2f},
    {0,0,0,0, 1, 0,-2, 2, 0.2f},
    {0,0,0,0, 1, 1,-2, 2, 0.2f},
    {0,0,0,0, 1, 1,-2, 2, 0.2f},
    {1,-2,-2, 2, 1, 2,-1, 2, 1.f/9.f},
    {1,-1,-2, 2, 0,0,0,0, 0.2f},
    {1, 0,-2, 2, 0,0,0,0, 0.2f},
    {1, 1,-2, 2, 0,0,0,0, 0.2f},
    {1, 2,-2, 2, 1, 2,-2, 1, 1.f/9.f},
    // ring7 (24)
    {1,-3,-3,11, 1,-3,-2,21, 1.f/39.f},
    {1,-2,-3,11, 0,0,0,0, 1.f/15.f},
    {1,-1,-3,11, 0,0,0,0, 1.f/15.f},
    {1, 0,-3,11, 0,0,0,0, 1.f/15.f},
    {1, 1,-3,11, 0,0,0,0, 1.f/15.f},
    {1, 2,-3,11, 0,0,0,0, 1.f/15.f},
    {1, 3,-3,11, 1,-3,-21, 2, 1.f/39.f},
    {0,0,0,0, 1,-2,-3,21, 0.04f},
    {0,0,0,0, 1,-2,-21,3, 0.04f},
    {0,0,0,0, 1,-1,-3,21, 0.04f},
    {0,0,0,0, 1,-1,-21,3, 0.04f},
    {0,0,0,0, 1, 0,-3,21, 0.04f},
    {0,0,0,0, 1, 0,-21,3, 0.04f},
    {0,0,0,0, 1, 1,-3,21, 0.04f},
    {0,0,0,0, 1, 1,-21,3, 0.04f},
    {0,0,0,0, 1, 2,-3,21, 0.04f},
    {0,0,0,0, 1, 2,-21,3, 0.04f},
    {1,-3,-11,3, 1, 3,-2,21, 1.f/39.f},
    {1,-2,-11,3, 0,0,0,0, 1.f/15.f},
    {1,-1,-11,3, 0,0,0,0, 1.f/15.f},
    {1, 0,-11,3, 0,0,0,0, 1.f/15.f},
    {1, 1,-11,3, 0,0,0,0, 1.f/15.f},
    {1, 2,-11,3, 0,0,0,0, 1.f/15.f},
    {1, 3,-11,3, 1, 3,-21,2, 1.f/39.f},
};

// reflect-pad(3) + clip index map; valid for u in [-21, 213]
__device__ __forceinline__ int mapIdx(int u) {
    if (u < 0) { u = -u; if (u > 3) u = 3; }
    else if (u > 191) { u = 382 - u; if (u < 188) u = 188; }
    return u;
}

// RNE fp32->bf16 bits (native; pairs fuse to v_cvt_pk_bf16_f32)
__device__ __forceinline__ ushort f2bf(float f) {
    __hip_bfloat16 h = __float2bfloat16(f);
    return __builtin_bit_cast(ushort, h);
}

// Merged prep (256-thread blocks):
//   [0, PH_B): PH rows via wave-parallel shfl scans (coalesced loads AND writes)
//   [PH_B, PH_B+PV_B): PV columns, thread-serial (already coalesced)
//   [PH_B+PV_B, PREP_B): weight bf16 conversion
__global__ __launch_bounds__(256)
void prep(const float* __restrict__ x, const float* __restrict__ wgt,
          float* __restrict__ pvg, float* __restrict__ phg, ushort* __restrict__ wbf)
{
    const int bid = blockIdx.x, tid = threadIdx.x;
    if (bid < PH_B) {
        // ---- PH: one wave per (plane,q) row; 235-elem scan in 4 chunks of 64 ----
        const int lane = tid & 63;
        const int row  = bid * 4 + (tid >> 6);
        const int plane = row / 198;
        const int q     = row - plane * 198;
        const float* xp = x + (size_t)plane * HW;
        const int rsrc  = mapIdx(q - 3) * Ww;
        float* ph = phg + (size_t)plane * PHG_PLANE + (size_t)q * 236;
        if (lane == 0) ph[0] = 0.f;
        float carry = 0.f;
#pragma unroll
        for (int ck = 0; ck < 4; ++ck) {
            const int idx = ck * 64 + lane;
            float v = (idx < 235) ? xp[rsrc + mapIdx(idx - 21)] : 0.f;
#pragma unroll
            for (int d = 1; d < 64; d <<= 1) {
                float t2 = __shfl_up(v, d);
                if (lane >= d) v += t2;
            }
            if (idx < 235) ph[idx + 1] = v + carry;
            carry += __shfl(v, 63);
        }
        return;
    }
    if (bid < PH_B + PV_B) {
        const int t = (bid - PH_B) * 256 + tid;
        if (t >= NPL * 198) return;
        const int plane = t / 198;
        const int q     = t - plane * 198;
        const float* xp = x + (size_t)plane * HW;
        const int wsrc = mapIdx(q - 3);
        float* pv = pvg + (size_t)plane * PVG_PLANE + q;
        float r = 0.f;
        pv[0] = 0.f;
        for (int t0 = 0; t0 < 235; t0 += 5) {
            float v0 = xp[mapIdx(t0 - 21) * Ww + wsrc];
            float v1 = xp[mapIdx(t0 - 20) * Ww + wsrc];
            float v2 = xp[mapIdx(t0 - 19) * Ww + wsrc];
            float v3 = xp[mapIdx(t0 - 18) * Ww + wsrc];
            float v4 = xp[mapIdx(t0 - 17) * Ww + wsrc];
            float* pd = pv + (size_t)(t0 + 1) * 198;
            r += v0; pd[0]   = r;
            r += v1; pd[198] = r;
            r += v2; pd[396] = r;
            r += v3; pd[594] = r;
            r += v4; pd[792] = r;
        }
        return;
    }
    {
        const int t = (bid - PH_B - PV_B) * 256 + tid;   // 65536 entries
        const int k = t & 63, o = (t >> 6) & 63, c = t >> 12;
        wbf[t] = (k < 49) ? f2bf(wgt[o * 784 + c * 49 + k]) : (ushort)0;
    }
}

// NC = channels per block; DIRECT: write out+bias, else fp32 partial to dst.
template<int NC, bool DIRECT>
__global__ __launch_bounds__(NT, 3)
void fova23(const ushort* __restrict__ wbf, const float* __restrict__ bias,
            const float* __restrict__ pvg, const float* __restrict__ phg,
            float* __restrict__ dst)
{
    constexpr int HALVES = Cc / NC;
    __shared__ ushort featB[NT][66];   // 16896 B
    __shared__ ushort wlds[64][72];    //  9216 B
    __shared__ float  pvt[27][40];     //  4320 B   (total 30432 -> 5 blocks/CU)

    const int tid  = threadIdx.x;
    const int lane = tid & 63;
    const int wv   = tid >> 6;          // wave id 0/1
    const int w0   = blockIdx.x * TW;
    const int h0   = blockIdx.y * TH;
    const int bz   = blockIdx.z;
    const int b    = (HALVES == 1) ? bz : (bz >> 1);
    const int half = (HALVES == 1) ? 0  : (bz & 1);
    const int c0   = half * NC;
    const int ph_  = tid >> 5;          // pixel row 0..3 (tid == pixel id)
    const int pw   = tid & 31;
    const int h    = h0 + ph_, w = w0 + pw;

    float4v acc[4][4];
#pragma unroll
    for (int i = 0; i < 4; ++i)
#pragma unroll
        for (int j = 0; j < 4; ++j) acc[i][j] = (float4v)(0.f);

#pragma unroll
    for (int f = 49; f < 64; ++f) featB[tid][f] = 0;

    // sources (advance by plane stride per c)
    const float* pvsrc = pvg + (size_t)(b * Cc + c0) * PVG_PLANE + (size_t)(h0 + 10) * 198 + w0;
    const float* phb   = phg + (size_t)(b * Cc + c0) * PHG_PLANE + (size_t)(h + 3) * 236 + (w + 21);
    const ushort* wsrc0 = wbf + (c0 << 12) + tid * 32;

    // ---- prologue: stage pvt(c0) ----
    for (int idx = tid; idx < 27 * 38; idx += NT) {
        int r = idx / 38, c = idx - r * 38;
        pvt[r][c] = pvsrc[r * 198 + c];
    }
    __syncthreads();

    for (int cc = 0; cc < NC; ++cc) {
        // ---- W(c) regs: issue early ----
        short8v wreg[4];
#pragma unroll
        for (int q = 0; q < 4; ++q)
            wreg[q] = *(const short8v*)(&wsrc0[q * 8]);

        // ---- features: V from pvt (LDS), H from phg (global, L1-resident tile) ----
        {
            auto FV = [&](int f) -> float {
                float s = 0.f;
                if (FT[f].hasV)
                    s += pvt[ph_ + FT[f].vi1 + 12][pw + 3 + FT[f].vdj]
                       - pvt[ph_ + FT[f].vi0 + 11][pw + 3 + FT[f].vdj];
                if (FT[f].hasH)
                    s += phb[FT[f].hdi * 236 + (FT[f].hj1 + 1)] - phb[FT[f].hdi * 236 + FT[f].hj0];
                return s * FT[f].inv_n;
            };
            uint* fb32 = reinterpret_cast<uint*>(&featB[tid][0]);
#pragma unroll
            for (int j = 0; j < 24; ++j)
                fb32[j] = (uint)f2bf(FV(2 * j)) | ((uint)f2bf(FV(2 * j + 1)) << 16);
            featB[tid][48] = f2bf(FV(48));
        }
        // ---- wlds write ----
        {
            const int base = tid * 4;
#pragma unroll
            for (int q = 0; q < 4; ++q) {
                const int idx = base + q;
                *(short8v*)(&wlds[idx >> 3][(idx & 7) * 8]) = wreg[q];
            }
        }
        __syncthreads();   // featB/wlds ready; all pvt reads done

        // ---- stage-loads pvt(c+1): issue BEFORE MFMA ----
        float pvr[9];
        const bool more = (cc + 1 < NC);
        if (more) {
            const float* pvn = pvsrc + PVG_PLANE;
#pragma unroll
            for (int k = 0; k < 9; ++k) {
                int idx = tid + k * NT;
                if (idx < 27 * 38) pvr[k] = pvn[(idx / 38) * 198 + (idx % 38)];
            }
        }

        // ---- MFMA(c): A from wlds (b128), B from featB ----
        {
            const int olo = lane & 15, kg = lane >> 4;
#pragma unroll
            for (int kc = 0; kc < 2; ++kc) {
                const int k0 = kc * 32 + kg * 8;
                short8v afr[4];
#pragma unroll
                for (int ob = 0; ob < 4; ++ob) {
                    const int o = ob * 16 + olo;
                    afr[ob] = *(const short8v*)(&wlds[o][k0]);
                }
                short8v bfr[4];
#pragma unroll
                for (int nb = 0; nb < 4; ++nb) {
                    const int p = wv * 64 + nb * 16 + olo;
                    const uint* bp = (const uint*)(&featB[p][k0]);
                    uint4 u;
                    u.x = bp[0]; u.y = bp[1]; u.z = bp[2]; u.w = bp[3];
                    bfr[nb] = __builtin_bit_cast(short8v, u);
                }
#pragma unroll
                for (int ob = 0; ob < 4; ++ob)
#pragma unroll
                    for (int nb = 0; nb < 4; ++nb)
                        acc[ob][nb] = __builtin_amdgcn_mfma_f32_16x16x32_bf16(
                            afr[ob], bfr[nb], acc[ob][nb], 0, 0, 0);
            }
        }

        // ---- write pvt(c+1) ----
        if (more) {
#pragma unroll
            for (int k = 0; k < 9; ++k) {
                int idx = tid + k * NT;
                if (idx < 27 * 38) pvt[idx / 38][idx % 38] = pvr[k];
            }
        }
        __syncthreads();   // MFMA done; pvt(c+1) ready

        pvsrc += PVG_PLANE; phb += PHG_PLANE; wsrc0 += 4096;
    }

    // ---- epilogue ----
    float* dbase = DIRECT ? dst : (dst + (size_t)half * PLANE);
#pragma unroll
    for (int ob = 0; ob < 4; ++ob)
#pragma unroll
        for (int nb = 0; nb < 4; ++nb) {
            const int p = wv * 64 + nb * 16 + (lane & 15);
            const int hh = h0 + (p >> 5), ww2 = w0 + (p & 31);
            const int o0 = ob * 16 + ((lane >> 4) << 2);
            float4v a = acc[ob][nb];
#pragma unroll
            for (int r = 0; r < 4; ++r) {
                const int o = o0 + r;
                float v = DIRECT ? (a[r] + bias[o]) : a[r];
                dbase[(((size_t)b * Oo + o) * Hh + hh) * Ww + ww2] = v;
            }
        }
}

// out = p0 + p1 + bias (memory-bound, float4, grid-stride)
__global__ __launch_bounds__(256)
void reduce2(const float4* __restrict__ p, const float* __restrict__ bias,
             float4* __restrict__ out)
{
    const int n4 = (int)(PLANE / 4);
    for (int i = blockIdx.x * 256 + threadIdx.x; i < n4; i += gridDim.x * 256) {
        float4 a = p[i];
        float4 b = p[i + n4];
        const int o = (i / 9216) & 63;
        const float bo = bias[o];
        float4 r;
        r.x = a.x + b.x + bo; r.y = a.y + b.y + bo;
        r.z = a.z + b.z + bo; r.w = a.w + b.w + bo;
        out[i] = r;
    }
}

} // namespace

extern "C" void kernel_launch(void* const* d_in, const int* in_sizes, int n_in,
                              void* d_out, int out_size, void* d_ws, size_t ws_size,
                              hipStream_t stream) {
    (void)in_sizes; (void)n_in; (void)out_size;
    const float* x    = (const float*)d_in[0];
    const float* wgt  = (const float*)d_in[1];
    const float* bias = (const float*)d_in[2];
    float* out        = (float*)d_out;

    float* pvg  = (float*)d_ws;
    float* phg  = pvg + (size_t)NPL * PVG_PLANE;
    ushort* wbf = (ushort*)(phg + (size_t)NPL * PHG_PLANE);

    prep<<<dim3(PREP_B), dim3(256), 0, stream>>>(x, wgt, pvg, phg, wbf);

    dim3 block(NT);
    if (ws_size >= NEED_FULL) {
        float* part = (float*)d_ws + PREFIX_FLOATS + WBF_FLOATS;
        dim3 grid(Ww / TW, Hh / TH, Bb * 2);          // 2304 blocks, 8 channels each
        fova23<8, false><<<grid, block, 0, stream>>>(wbf, bias, pvg, phg, part);
        reduce2<<<dim3(2048), dim3(256), 0, stream>>>((const float4*)part, bias, (float4*)out);
    } else {
        dim3 grid(Ww / TW, Hh / TH, Bb);              // 1152 blocks, 16 channels
        fova23<16, true><<<grid, block, 0, stream>>>(wbf, bias, pvg, phg, out);
    }
}

// Round 24
// 132.705 us; speedup vs baseline: 1.0909x; 1.0909x over previous
//
#include <hip/hip_runtime.h>
#include <hip/hip_bf16.h>

typedef __attribute__((ext_vector_type(8))) short short8v;   // bf16x8 fragment
typedef __attribute__((ext_vector_type(4))) float float4v;   // fp32x4 accum
typedef unsigned short ushort;
typedef unsigned int uint;

namespace {

constexpr int Hh = 192, Ww = 192, Cc = 16, Oo = 64, Bb = 4;
constexpr int TH = 4, TW = 32, NT = 128;     // 4x32 pixel tile, 128 threads (2 waves)
constexpr int HW = Hh * Ww;                  // 36864
constexpr int NPL = Bb * Cc;                 // 64 planes
constexpr int PVG_PLANE = 236 * 198;         // col-prefix plane
constexpr int PHG_PLANE = 198 * 236;         // row-prefix plane
constexpr size_t PLANE = (size_t)Bb * Oo * HW;                 // 9437184 floats
constexpr size_t PREFIX_FLOATS = (size_t)NPL * (PVG_PLANE + PHG_PLANE);
constexpr size_t WBF_FLOATS = 65536 / 2;
constexpr size_t NEED_FULL = (PREFIX_FLOATS + WBF_FLOATS + 2 * PLANE) * 4;  // 99,553,280
// prep decomposition (256-thread blocks):
constexpr int PH_ROWS  = NPL * 198;          // 12672 rows, 1 wave each
constexpr int PH_B     = PH_ROWS / 4;        // 3168 blocks (4 waves/block)
constexpr int PV_B     = (NPL * 198 + 255) / 256;   // 50
constexpr int WP_B     = 65536 / 256;        // 256
constexpr int PREP_B   = PH_B + PV_B + WP_B;

// reflect-pad(3) + clip index map; valid for u in [-21, 213]
__device__ __forceinline__ int mapIdx(int u) {
    if (u < 0) { u = -u; if (u > 3) u = 3; }
    else if (u > 191) { u = 382 - u; if (u < 188) u = 188; }
    return u;
}

// RNE fp32->bf16 bits (native; pairs fuse to v_cvt_pk_bf16_f32)
__device__ __forceinline__ ushort f2bf(float f) {
    __hip_bfloat16 h = __float2bfloat16(f);
    return __builtin_bit_cast(ushort, h);
}

// Merged prep (256-thread blocks): PH wave-scans / PV serial / weight conversion.
__global__ __launch_bounds__(256)
void prep(const float* __restrict__ x, const float* __restrict__ wgt,
          float* __restrict__ pvg, float* __restrict__ phg, ushort* __restrict__ wbf)
{
    const int bid = blockIdx.x, tid = threadIdx.x;
    if (bid < PH_B) {
        const int lane = tid & 63;
        const int row  = bid * 4 + (tid >> 6);
        const int plane = row / 198;
        const int q     = row - plane * 198;
        const float* xp = x + (size_t)plane * HW;
        const int rsrc  = mapIdx(q - 3) * Ww;
        float* ph = phg + (size_t)plane * PHG_PLANE + (size_t)q * 236;
        if (lane == 0) ph[0] = 0.f;
        float carry = 0.f;
#pragma unroll
        for (int ck = 0; ck < 4; ++ck) {
            const int idx = ck * 64 + lane;
            float v = (idx < 235) ? xp[rsrc + mapIdx(idx - 21)] : 0.f;
#pragma unroll
            for (int d = 1; d < 64; d <<= 1) {
                float t2 = __shfl_up(v, d);
                if (lane >= d) v += t2;
            }
            if (idx < 235) ph[idx + 1] = v + carry;
            carry += __shfl(v, 63);
        }
        return;
    }
    if (bid < PH_B + PV_B) {
        const int t = (bid - PH_B) * 256 + tid;
        if (t >= NPL * 198) return;
        const int plane = t / 198;
        const int q     = t - plane * 198;
        const float* xp = x + (size_t)plane * HW;
        const int wsrc = mapIdx(q - 3);
        float* pv = pvg + (size_t)plane * PVG_PLANE + q;
        float r = 0.f;
        pv[0] = 0.f;
        for (int t0 = 0; t0 < 235; t0 += 5) {
            float v0 = xp[mapIdx(t0 - 21) * Ww + wsrc];
            float v1 = xp[mapIdx(t0 - 20) * Ww + wsrc];
            float v2 = xp[mapIdx(t0 - 19) * Ww + wsrc];
            float v3 = xp[mapIdx(t0 - 18) * Ww + wsrc];
            float v4 = xp[mapIdx(t0 - 17) * Ww + wsrc];
            float* pd = pv + (size_t)(t0 + 1) * 198;
            r += v0; pd[0]   = r;
            r += v1; pd[198] = r;
            r += v2; pd[396] = r;
            r += v3; pd[594] = r;
            r += v4; pd[792] = r;
        }
        return;
    }
    {
        const int t = (bid - PH_B - PV_B) * 256 + tid;   // 65536 entries
        const int k = t & 63, o = (t >> 6) & 63, c = t >> 12;
        wbf[t] = (k < 49) ? f2bf(wgt[o * 784 + c * 49 + k]) : (ushort)0;
    }
}

// NC = channels per block; DIRECT: write out+bias, else fp32 partial to dst.
template<int NC, bool DIRECT>
__global__ __launch_bounds__(NT, 3)
void fova24(const ushort* __restrict__ wbf, const float* __restrict__ bias,
            const float* __restrict__ pvg, const float* __restrict__ phg,
            float* __restrict__ dst)
{
    constexpr int HALVES = Cc / NC;
    __shared__ __align__(16) ushort featB[NT][72];   // 18432 B, 144B rows (16B-aligned)
    __shared__ __align__(16) ushort wlds[64][72];    //  9216 B
    __shared__ float  pvt[27][40];                   //  4320 B
    __shared__ float  pht[10][76];                   //  3040 B  (total 35008 -> 4 blk/CU)

    const int tid  = threadIdx.x;
    const int lane = tid & 63;
    const int wv   = tid >> 6;          // wave id 0/1
    const int w0   = blockIdx.x * TW;
    const int h0   = blockIdx.y * TH;
    const int bz   = blockIdx.z;
    const int b    = (HALVES == 1) ? bz : (bz >> 1);
    const int half = (HALVES == 1) ? 0  : (bz & 1);
    const int c0   = half * NC;
    const int ph_  = tid >> 5;          // pixel row 0..3 (tid == pixel id)
    const int pw   = tid & 31;

    float4v acc[4][4];
#pragma unroll
    for (int i = 0; i < 4; ++i)
#pragma unroll
        for (int j = 0; j < 4; ++j) acc[i][j] = (float4v)(0.f);

#pragma unroll
    for (int f = 49; f < 64; ++f) featB[tid][f] = 0;

    const float* pvsrc = pvg + (size_t)(b * Cc + c0) * PVG_PLANE + (size_t)(h0 + 10) * 198 + w0;
    const float* phsrc = phg + (size_t)(b * Cc + c0) * PHG_PLANE + (size_t)h0 * 236 + w0;
    const ushort* wsrc0 = wbf + (c0 << 12) + tid * 32;

    // ---- prologue: stage tiles(c0) ----
    for (int idx = tid; idx < 27 * 38; idx += NT) {
        int r = idx / 38, c = idx - r * 38;
        pvt[r][c] = pvsrc[r * 198 + c];
    }
    for (int idx = tid; idx < 10 * 75; idx += NT) {
        int r = idx / 75, c = idx - r * 75;
        pht[r][c] = phsrc[r * 236 + c];
    }
    __syncthreads();

    for (int cc = 0; cc < NC; ++cc) {
        // ---- W(c) regs: issue early ----
        short8v wreg[4];
#pragma unroll
        for (int q = 0; q < 4; ++q)
            wreg[q] = *(const short8v*)(&wsrc0[q * 8]);

        // ---- features: deduped reads, shared diffs (bit-identical to fova22) ----
        {
            // V: per column j (vdj = j-3) load distinct rows once
            float dwn[7], up_[7], r5v[5], inn[3][3];
#pragma unroll
            for (int j = 0; j < 7; ++j) {
                const int cj = pw + j;
                float m12 = pvt[ph_ +  0][cj];   // o=-12
                float m4  = pvt[ph_ +  8][cj];   // o=-4
                float p3  = pvt[ph_ + 15][cj];   // o=+3
                float p11 = pvt[ph_ + 23][cj];   // o=+11
                dwn[j] = p11 - m4;               // ring7 (vi0=-3,vi1=11)
                up_[j] = p3 - m12;               // ring7 (vi0=-11,vi1=3)
                if (j >= 1 && j <= 5) {
                    float m3 = pvt[ph_ +  9][cj];
                    float p2 = pvt[ph_ + 14][cj];
                    r5v[j - 1] = p2 - m3;        // ring5 (vi0=-2,vi1=2)
                }
                if (j >= 2 && j <= 4) {
                    float m2 = pvt[ph_ + 10][cj];
                    float m1 = pvt[ph_ + 11][cj];
                    float z0 = pvt[ph_ + 12][cj];
                    float p1 = pvt[ph_ + 13][cj];
                    inn[j - 2][0] = m1 - m2;     // v=-1
                    inn[j - 2][1] = z0 - m1;     // v=0
                    inn[j - 2][2] = p1 - z0;     // v=+1
                }
            }
            // H: per row load distinct cols once
            const int CB = pw + 21;
            float h5a_m, h5b_m, h5a_p, h5b_p, h5c[3];
            float h7d[5], h7e[5], h7f_m, h7g_m, h7f_p, h7g_p;
            {
                const float* r = &pht[ph_][0];                  // hdi=-3
                h7f_m = r[CB + 22] - r[CB - 2];
                h7g_m = r[CB + 3]  - r[CB - 21];
            }
            {
                const float* r = &pht[ph_ + 6][0];              // hdi=+3
                h7f_p = r[CB + 22] - r[CB - 2];
                h7g_p = r[CB + 3]  - r[CB - 21];
            }
            {
                const float* r = &pht[ph_ + 1][0];              // hdi=-2
                h5a_m = r[CB + 3]  - r[CB - 1];
                h5b_m = r[CB + 2]  - r[CB - 2];
                h7d[0] = r[CB + 22] - r[CB - 3];
                h7e[0] = r[CB + 4]  - r[CB - 21];
            }
            {
                const float* r = &pht[ph_ + 5][0];              // hdi=+2
                h5a_p = r[CB + 3]  - r[CB - 1];
                h5b_p = r[CB + 2]  - r[CB - 2];
                h7d[4] = r[CB + 22] - r[CB - 3];
                h7e[4] = r[CB + 4]  - r[CB - 21];
            }
#pragma unroll
            for (int k = 0; k < 3; ++k) {                       // hdi=-1,0,1
                const float* r = &pht[ph_ + 2 + k][0];
                h5c[k]     = r[CB + 3]  - r[CB - 2];
                h7d[k + 1] = r[CB + 22] - r[CB - 3];
                h7e[k + 1] = r[CB + 4]  - r[CB - 21];
            }

            // assemble + pack (pairs fuse to v_cvt_pk_bf16_f32)
            auto pk = [](float a, float bq) -> uint {
                return (uint)f2bf(a) | ((uint)f2bf(bq) << 16);
            };
            const float n9 = 1.f / 9.f, n15 = 1.f / 15.f, n39 = 1.f / 39.f;
            float s14 = h5c[0] * 0.2f, s16 = h5c[1] * 0.2f, s18 = h5c[2] * 0.2f;
            uint4 U;
            uint4* fb = reinterpret_cast<uint4*>(&featB[tid][0]);
            U.x = pk(inn[0][0], inn[1][0]);                    // f0,f1
            U.y = pk(inn[2][0], inn[0][1]);                    // f2,f3
            U.z = pk(inn[1][1], inn[2][1]);                    // f4,f5
            U.w = pk(inn[0][2], inn[1][2]);                    // f6,f7
            fb[0] = U;
            U.x = pk(inn[2][2], (r5v[0] + h5a_m) * n9);        // f8,f9
            U.y = pk(r5v[1] * 0.2f, r5v[2] * 0.2f);            // f10,f11
            U.z = pk(r5v[3] * 0.2f, (r5v[4] + h5b_m) * n9);    // f12,f13
            U.w = pk(s14, s14);                                 // f14,f15
            fb[1] = U;
            U.x = pk(s16, s16);                                 // f16,f17
            U.y = pk(s18, s18);                                 // f18,f19
            U.z = pk((r5v[0] + h5a_p) * n9, r5v[1] * 0.2f);    // f20,f21
            U.w = pk(r5v[2] * 0.2f, r5v[3] * 0.2f);            // f22,f23
            fb[2] = U;
            U.x = pk((r5v[4] + h5b_p) * n9, (dwn[0] + h7f_m) * n39);  // f24,f25
            U.y = pk(dwn[1] * n15, dwn[2] * n15);              // f26,f27
            U.z = pk(dwn[3] * n15, dwn[4] * n15);              // f28,f29
            U.w = pk(dwn[5] * n15, (dwn[6] + h7g_m) * n39);    // f30,f31
            fb[3] = U;
            U.x = pk(h7d[0] * 0.04f, h7e[0] * 0.04f);          // f32,f33
            U.y = pk(h7d[1] * 0.04f, h7e[1] * 0.04f);          // f34,f35
            U.z = pk(h7d[2] * 0.04f, h7e[2] * 0.04f);          // f36,f37
            U.w = pk(h7d[3] * 0.04f, h7e[3] * 0.04f);          // f38,f39
            fb[4] = U;
            U.x = pk(h7d[4] * 0.04f, h7e[4] * 0.04f);          // f40,f41
            U.y = pk((up_[0] + h7f_p) * n39, up_[1] * n15);    // f42,f43
            U.z = pk(up_[2] * n15, up_[3] * n15);              // f44,f45
            U.w = pk(up_[4] * n15, up_[5] * n15);              // f46,f47
            fb[5] = U;
            featB[tid][48] = f2bf((up_[6] + h7g_p) * n39);     // f48
        }
        // ---- wlds write ----
        {
            const int base = tid * 4;
#pragma unroll
            for (int q = 0; q < 4; ++q) {
                const int idx = base + q;
                *(short8v*)(&wlds[idx >> 3][(idx & 7) * 8]) = wreg[q];
            }
        }
        __syncthreads();   // featB/wlds ready; all tile reads done

        // ---- stage-loads(c+1): issue BEFORE MFMA ----
        float pvr[9], phr[6];
        const bool more = (cc + 1 < NC);
        if (more) {
            const float* pvn = pvsrc + PVG_PLANE;
            const float* phn = phsrc + PHG_PLANE;
#pragma unroll
            for (int k = 0; k < 9; ++k) {
                int idx = tid + k * NT;
                if (idx < 27 * 38) pvr[k] = pvn[(idx / 38) * 198 + (idx % 38)];
            }
#pragma unroll
            for (int k = 0; k < 6; ++k) {
                int idx = tid + k * NT;
                if (idx < 10 * 75) phr[k] = phn[(idx / 75) * 236 + (idx % 75)];
            }
        }

        // ---- MFMA(c): A from wlds (b128), B from featB (single b128 now) ----
        {
            const int olo = lane & 15, kg = lane >> 4;
#pragma unroll
            for (int kc = 0; kc < 2; ++kc) {
                const int k0 = kc * 32 + kg * 8;
                short8v afr[4];
#pragma unroll
                for (int ob = 0; ob < 4; ++ob) {
                    const int o = ob * 16 + olo;
                    afr[ob] = *(const short8v*)(&wlds[o][k0]);
                }
                short8v bfr[4];
#pragma unroll
                for (int nb = 0; nb < 4; ++nb) {
                    const int p = wv * 64 + nb * 16 + olo;
                    bfr[nb] = *(const short8v*)(&featB[p][k0]);   // 16B-aligned: 1x b128
                }
#pragma unroll
                for (int ob = 0; ob < 4; ++ob)
#pragma unroll
                    for (int nb = 0; nb < 4; ++nb)
                        acc[ob][nb] = __builtin_amdgcn_mfma_f32_16x16x32_bf16(
                            afr[ob], bfr[nb], acc[ob][nb], 0, 0, 0);
            }
        }

        // ---- write tiles(c+1) ----
        if (more) {
#pragma unroll
            for (int k = 0; k < 9; ++k) {
                int idx = tid + k * NT;
                if (idx < 27 * 38) pvt[idx / 38][idx % 38] = pvr[k];
            }
#pragma unroll
            for (int k = 0; k < 6; ++k) {
                int idx = tid + k * NT;
                if (idx < 10 * 75) pht[idx / 75][idx % 75] = phr[k];
            }
        }
        __syncthreads();   // MFMA done; tiles(c+1) ready

        pvsrc += PVG_PLANE; phsrc += PHG_PLANE; wsrc0 += 4096;
    }

    // ---- epilogue ----
    float* dbase = DIRECT ? dst : (dst + (size_t)half * PLANE);
#pragma unroll
    for (int ob = 0; ob < 4; ++ob)
#pragma unroll
        for (int nb = 0; nb < 4; ++nb) {
            const int p = wv * 64 + nb * 16 + (lane & 15);
            const int hh = h0 + (p >> 5), ww2 = w0 + (p & 31);
            const int o0 = ob * 16 + ((lane >> 4) << 2);
            float4v a = acc[ob][nb];
#pragma unroll
            for (int r = 0; r < 4; ++r) {
                const int o = o0 + r;
                float v = DIRECT ? (a[r] + bias[o]) : a[r];
                dbase[(((size_t)b * Oo + o) * Hh + hh) * Ww + ww2] = v;
            }
        }
}

// out = p0 + p1 + bias (memory-bound, float4, grid-stride)
__global__ __launch_bounds__(256)
void reduce2(const float4* __restrict__ p, const float* __restrict__ bias,
             float4* __restrict__ out)
{
    const int n4 = (int)(PLANE / 4);
    for (int i = blockIdx.x * 256 + threadIdx.x; i < n4; i += gridDim.x * 256) {
        float4 a = p[i];
        float4 b = p[i + n4];
        const int o = (i / 9216) & 63;
        const float bo = bias[o];
        float4 r;
        r.x = a.x + b.x + bo; r.y = a.y + b.y + bo;
        r.z = a.z + b.z + bo; r.w = a.w + b.w + bo;
        out[i] = r;
    }
}

} // namespace

extern "C" void kernel_launch(void* const* d_in, const int* in_sizes, int n_in,
                              void* d_out, int out_size, void* d_ws, size_t ws_size,
                              hipStream_t stream) {
    (void)in_sizes; (void)n_in; (void)out_size;
    const float* x    = (const float*)d_in[0];
    const float* wgt  = (const float*)d_in[1];
    const float* bias = (const float*)d_in[2];
    float* out        = (float*)d_out;

    float* pvg  = (float*)d_ws;
    float* phg  = pvg + (size_t)NPL * PVG_PLANE;
    ushort* wbf = (ushort*)(phg + (size_t)NPL * PHG_PLANE);

    prep<<<dim3(PREP_B), dim3(256), 0, stream>>>(x, wgt, pvg, phg, wbf);

    dim3 block(NT);
    if (ws_size >= NEED_FULL) {
        float* part = (float*)d_ws + PREFIX_FLOATS + WBF_FLOATS;
        dim3 grid(Ww / TW, Hh / TH, Bb * 2);          // 2304 blocks, 8 channels each
        fova24<8, false><<<grid, block, 0, stream>>>(wbf, bias, pvg, phg, part);
        reduce2<<<dim3(2048), dim3(256), 0, stream>>>((const float4*)part, bias, (float4*)out);
    } else {
        dim3 grid(Ww / TW, Hh / TH, Bb);              // 1152 blocks, 16 channels
        fova24<16, true><<<grid, block, 0, stream>>>(wbf, bias, pvg, phg, out);
    }
}

// Round 25
// 106.807 us; speedup vs baseline: 1.3554x; 1.2425x over previous
//
#include <hip/hip_runtime.h>
#include <hip/hip_bf16.h>

typedef __attribute__((ext_vector_type(8))) short short8v;   // bf16x8 fragment
typedef __attribute__((ext_vector_type(4))) float float4v;   // fp32x4 accum
typedef unsigned short ushort;
typedef unsigned int uint;

namespace {

constexpr int Hh = 192, Ww = 192, Cc = 16, Oo = 64, Bb = 4;
constexpr int TH = 4, TW = 32, NT = 128;     // 4x32 pixel tile, 128 threads (2 waves)
constexpr int HW = Hh * Ww;                  // 36864
constexpr int NPL = Bb * Cc;                 // 64 planes
constexpr int PVG_PLANE = 236 * 198;         // col-prefix plane
constexpr int PHG_PLANE = 198 * 236;         // row-prefix plane
constexpr size_t PLANE = (size_t)Bb * Oo * HW;                 // 9437184 floats
constexpr size_t PREFIX_FLOATS = (size_t)NPL * (PVG_PLANE + PHG_PLANE);
constexpr size_t WBF_FLOATS = 65536 / 2;
constexpr size_t NEED_FULL = (PREFIX_FLOATS + WBF_FLOATS + 2 * PLANE) * 4;  // 99,553,280
constexpr int NPREF_T = 2 * NPL * 198;       // 25344 prefix threads
constexpr int NPREF_B = (NPREF_T + 63) / 64; // 396
constexpr int NWPREP_B = 65536 / 64;         // 1024

// Each feature = (vertical segment sum) + (horizontal segment sum), scaled by 1/n.
struct FD { int hasV; int vdj, vi0, vi1; int hasH; int hdi, hj0, hj1; float inv_n; };

constexpr FD FT[49] = {
    // 9 inner taps (i,j) row-major, n=1 (as V-singles)
    {1,-1,-1,-1, 0,0,0,0, 1.f}, {1, 0,-1,-1, 0,0,0,0, 1.f}, {1, 1,-1,-1, 0,0,0,0, 1.f},
    {1,-1, 0, 0, 0,0,0,0, 1.f}, {1, 0, 0, 0, 0,0,0,0, 1.f}, {1, 1, 0, 0, 0,0,0,0, 1.f},
    {1,-1, 1, 1, 0,0,0,0, 1.f}, {1, 0, 1, 1, 0,0,0,0, 1.f}, {1, 1, 1, 1, 0,0,0,0, 1.f},
    // ring5 (16)
    {1,-2,-2, 2, 1,-2,-1, 2, 1.f/9.f},
    {1,-1,-2, 2, 0,0,0,0, 0.2f},
    {1, 0,-2, 2, 0,0,0,0, 0.2f},
    {1, 1,-2, 2, 0,0,0,0, 0.2f},
    {1, 2,-2, 2, 1,-2,-2, 1, 1.f/9.f},
    {0,0,0,0, 1,-1,-2, 2, 0.2f},
    {0,0,0,0, 1,-1,-2, 2, 0.2f},
    {0,0,0,0, 1, 0,-2, 2, 0.2f},
    {0,0,0,0, 1, 0,-2, 2, 0.2f},
    {0,0,0,0, 1, 1,-2, 2, 0.2f},
    {0,0,0,0, 1, 1,-2, 2, 0.2f},
    {1,-2,-2, 2, 1, 2,-1, 2, 1.f/9.f},
    {1,-1,-2, 2, 0,0,0,0, 0.2f},
    {1, 0,-2, 2, 0,0,0,0, 0.2f},
    {1, 1,-2, 2, 0,0,0,0, 0.2f},
    {1, 2,-2, 2, 1, 2,-2, 1, 1.f/9.f},
    // ring7 (24)
    {1,-3,-3,11, 1,-3,-2,21, 1.f/39.f},
    {1,-2,-3,11, 0,0,0,0, 1.f/15.f},
    {1,-1,-3,11, 0,0,0,0, 1.f/15.f},
    {1, 0,-3,11, 0,0,0,0, 1.f/15.f},
    {1, 1,-3,11, 0,0,0,0, 1.f/15.f},
    {1, 2,-3,11, 0,0,0,0, 1.f/15.f},
    {1, 3,-3,11, 1,-3,-21, 2, 1.f/39.f},
    {0,0,0,0, 1,-2,-3,21, 0.04f},
    {0,0,0,0, 1,-2,-21,3, 0.04f},
    {0,0,0,0, 1,-1,-3,21, 0.04f},
    {0,0,0,0, 1,-1,-21,3, 0.04f},
    {0,0,0,0, 1, 0,-3,21, 0.04f},
    {0,0,0,0, 1, 0,-21,3, 0.04f},
    {0,0,0,0, 1, 1,-3,21, 0.04f},
    {0,0,0,0, 1, 1,-21,3, 0.04f},
    {0,0,0,0, 1, 2,-3,21, 0.04f},
    {0,0,0,0, 1, 2,-21,3, 0.04f},
    {1,-3,-11,3, 1, 3,-2,21, 1.f/39.f},
    {1,-2,-11,3, 0,0,0,0, 1.f/15.f},
    {1,-1,-11,3, 0,0,0,0, 1.f/15.f},
    {1, 0,-11,3, 0,0,0,0, 1.f/15.f},
    {1, 1,-11,3, 0,0,0,0, 1.f/15.f},
    {1, 2,-11,3, 0,0,0,0, 1.f/15.f},
    {1, 3,-11,3, 1, 3,-21,2, 1.f/39.f},
};

// reflect-pad(3) + clip index map; valid for u in [-21, 213]
__device__ __forceinline__ int mapIdx(int u) {
    if (u < 0) { u = -u; if (u > 3) u = 3; }
    else if (u > 191) { u = 382 - u; if (u < 188) u = 188; }
    return u;
}

// RNE fp32->bf16 bits (native; pairs fuse to v_cvt_pk_bf16_f32)
__device__ __forceinline__ ushort f2bf(float f) {
    __hip_bfloat16 h = __float2bfloat16(f);
    return __builtin_bit_cast(ushort, h);
}

// Merged prep (R22-verbatim): blocks [0,396) build prefix planes; rest convert weights.
__global__ __launch_bounds__(64)
void prep(const float* __restrict__ x, const float* __restrict__ wgt,
          float* __restrict__ pvg, float* __restrict__ phg, ushort* __restrict__ wbf)
{
    if (blockIdx.x >= NPREF_B) {
        const int t = (blockIdx.x - NPREF_B) * 64 + threadIdx.x;   // 65536 entries
        const int k = t & 63, o = (t >> 6) & 63, c = t >> 12;
        wbf[t] = (k < 49) ? f2bf(wgt[o * 784 + c * 49 + k]) : (ushort)0;
        return;
    }
    const int t = blockIdx.x * 64 + threadIdx.x;       // 0..25343
    if (t >= NPREF_T) return;
    const bool isPV = t < NPL * 198;
    const int u = isPV ? t : t - NPL * 198;
    const int plane = u / 198;
    const int q     = u - plane * 198;
    const float* xp = x + (size_t)plane * HW;
    if (isPV) {
        const int wsrc = mapIdx(q - 3);
        float* pv = pvg + (size_t)plane * PVG_PLANE + q;
        float r = 0.f;
        pv[0] = 0.f;
        for (int t0 = 0; t0 < 235; t0 += 5) {
            float v0 = xp[mapIdx(t0 - 21) * Ww + wsrc];
            float v1 = xp[mapIdx(t0 - 20) * Ww + wsrc];
            float v2 = xp[mapIdx(t0 - 19) * Ww + wsrc];
            float v3 = xp[mapIdx(t0 - 18) * Ww + wsrc];
            float v4 = xp[mapIdx(t0 - 17) * Ww + wsrc];
            float* pd = pv + (size_t)(t0 + 1) * 198;
            r += v0; pd[0]   = r;
            r += v1; pd[198] = r;
            r += v2; pd[396] = r;
            r += v3; pd[594] = r;
            r += v4; pd[792] = r;
        }
    } else {
        const int rsrc = mapIdx(q - 3) * Ww;
        float* ph = phg + (size_t)plane * PHG_PLANE + (size_t)q * 236;
        float r = 0.f;
        ph[0] = 0.f;
        for (int t0 = 0; t0 < 235; t0 += 5) {
            float v0 = xp[rsrc + mapIdx(t0 - 21)];
            float v1 = xp[rsrc + mapIdx(t0 - 20)];
            float v2 = xp[rsrc + mapIdx(t0 - 19)];
            float v3 = xp[rsrc + mapIdx(t0 - 18)];
            float v4 = xp[rsrc + mapIdx(t0 - 17)];
            float* pd = ph + t0 + 1;
            r += v0; pd[0] = r;
            r += v1; pd[1] = r;
            r += v2; pd[2] = r;
            r += v3; pd[3] = r;
            r += v4; pd[4] = r;
        }
    }
}

// NC = channels per block; DIRECT: write out+bias, else fp32 partial to dst.
template<int NC, bool DIRECT>
__global__ __launch_bounds__(NT, 3)
void fova25(const ushort* __restrict__ wbf, const float* __restrict__ bias,
            const float* __restrict__ pvg, const float* __restrict__ phg,
            float* __restrict__ dst)
{
    constexpr int HALVES = Cc / NC;
    __shared__ __align__(16) ushort featB[NT][72];   // 18432 B, 144B rows (16B-aligned)
    __shared__ __align__(16) ushort wlds[64][72];    //  9216 B
    __shared__ float  pvt[27][40];                   //  4320 B
    __shared__ float  pht[10][76];                   //  3040 B  (total 35008 -> 4 blk/CU)

    const int tid  = threadIdx.x;
    const int lane = tid & 63;
    const int wv   = tid >> 6;          // wave id 0/1
    const int w0   = blockIdx.x * TW;
    const int h0   = blockIdx.y * TH;
    const int bz   = blockIdx.z;
    const int b    = (HALVES == 1) ? bz : (bz >> 1);
    const int half = (HALVES == 1) ? 0  : (bz & 1);
    const int c0   = half * NC;
    const int ph_  = tid >> 5;          // pixel row 0..3 (tid == pixel id)
    const int pw   = tid & 31;

    float4v acc[4][4];
#pragma unroll
    for (int i = 0; i < 4; ++i)
#pragma unroll
        for (int j = 0; j < 4; ++j) acc[i][j] = (float4v)(0.f);

#pragma unroll
    for (int f = 49; f < 64; ++f) featB[tid][f] = 0;

    const float* pvsrc = pvg + (size_t)(b * Cc + c0) * PVG_PLANE + (size_t)(h0 + 10) * 198 + w0;
    const float* phsrc = phg + (size_t)(b * Cc + c0) * PHG_PLANE + (size_t)h0 * 236 + w0;
    const ushort* wsrc0 = wbf + (c0 << 12) + tid * 32;

    // ---- prologue: stage tiles(c0) ----
    for (int idx = tid; idx < 27 * 38; idx += NT) {
        int r = idx / 38, c = idx - r * 38;
        pvt[r][c] = pvsrc[r * 198 + c];
    }
    for (int idx = tid; idx < 10 * 75; idx += NT) {
        int r = idx / 75, c = idx - r * 75;
        pht[r][c] = phsrc[r * 236 + c];
    }
    __syncthreads();

    for (int cc = 0; cc < NC; ++cc) {
        // ---- W(c) regs: issue early ----
        short8v wreg[4];
#pragma unroll
        for (int q = 0; q < 4; ++q)
            wreg[q] = *(const short8v*)(&wsrc0[q * 8]);

        // ---- features from LDS tiles (R22-identical expressions/order); b128 stores ----
        {
            auto FV = [&](int f) -> float {
                float s = 0.f;
                if (FT[f].hasV)
                    s += pvt[ph_ + FT[f].vi1 + 12][pw + 3 + FT[f].vdj]
                       - pvt[ph_ + FT[f].vi0 + 11][pw + 3 + FT[f].vdj];
                if (FT[f].hasH)
                    s += pht[ph_ + 3 + FT[f].hdi][pw + 21 + FT[f].hj1 + 1]
                       - pht[ph_ + 3 + FT[f].hdi][pw + 21 + FT[f].hj0];
                return s * FT[f].inv_n;
            };
            auto pk = [](float a, float bq) -> uint {
                return (uint)f2bf(a) | ((uint)f2bf(bq) << 16);
            };
            uint4* fb = reinterpret_cast<uint4*>(&featB[tid][0]);
#pragma unroll
            for (int g = 0; g < 6; ++g) {
                uint4 U;
                U.x = pk(FV(g * 8 + 0), FV(g * 8 + 1));
                U.y = pk(FV(g * 8 + 2), FV(g * 8 + 3));
                U.z = pk(FV(g * 8 + 4), FV(g * 8 + 5));
                U.w = pk(FV(g * 8 + 6), FV(g * 8 + 7));
                fb[g] = U;
            }
            featB[tid][48] = f2bf(FV(48));
        }
        // ---- wlds write (W regs long since arrived) ----
        {
            const int base = tid * 4;
#pragma unroll
            for (int q = 0; q < 4; ++q) {
                const int idx = base + q;
                *(short8v*)(&wlds[idx >> 3][(idx & 7) * 8]) = wreg[q];
            }
        }
        __syncthreads();   // featB/wlds ready; all tile reads done

        // ---- stage-loads(c+1): issue BEFORE MFMA (latency hides under it) ----
        float pvr[9], phr[6];
        const bool more = (cc + 1 < NC);
        if (more) {
            const float* pvn = pvsrc + PVG_PLANE;
            const float* phn = phsrc + PHG_PLANE;
#pragma unroll
            for (int k = 0; k < 9; ++k) {
                int idx = tid + k * NT;
                if (idx < 27 * 38) pvr[k] = pvn[(idx / 38) * 198 + (idx % 38)];
            }
#pragma unroll
            for (int k = 0; k < 6; ++k) {
                int idx = tid + k * NT;
                if (idx < 10 * 75) phr[k] = phn[(idx / 75) * 236 + (idx % 75)];
            }
        }

        // ---- MFMA(c): A from wlds (b128), B from featB (single b128) ----
        {
            const int olo = lane & 15, kg = lane >> 4;
#pragma unroll
            for (int kc = 0; kc < 2; ++kc) {
                const int k0 = kc * 32 + kg * 8;
                short8v afr[4];
#pragma unroll
                for (int ob = 0; ob < 4; ++ob) {
                    const int o = ob * 16 + olo;
                    afr[ob] = *(const short8v*)(&wlds[o][k0]);
                }
                short8v bfr[4];
#pragma unroll
                for (int nb = 0; nb < 4; ++nb) {
                    const int p = wv * 64 + nb * 16 + olo;
                    bfr[nb] = *(const short8v*)(&featB[p][k0]);   // 16B-aligned b128
                }
#pragma unroll
                for (int ob = 0; ob < 4; ++ob)
#pragma unroll
                    for (int nb = 0; nb < 4; ++nb)
                        acc[ob][nb] = __builtin_amdgcn_mfma_f32_16x16x32_bf16(
                            afr[ob], bfr[nb], acc[ob][nb], 0, 0, 0);
            }
        }

        // ---- write tiles(c+1) (disjoint from featB/wlds; reads done pre-barrier) ----
        if (more) {
#pragma unroll
            for (int k = 0; k < 9; ++k) {
                int idx = tid + k * NT;
                if (idx < 27 * 38) pvt[idx / 38][idx % 38] = pvr[k];
            }
#pragma unroll
            for (int k = 0; k < 6; ++k) {
                int idx = tid + k * NT;
                if (idx < 10 * 75) pht[idx / 75][idx % 75] = phr[k];
            }
        }
        __syncthreads();   // MFMA done; tiles(c+1) ready

        pvsrc += PVG_PLANE; phsrc += PHG_PLANE; wsrc0 += 4096;
    }

    // ---- epilogue ----
    float* dbase = DIRECT ? dst : (dst + (size_t)half * PLANE);
#pragma unroll
    for (int ob = 0; ob < 4; ++ob)
#pragma unroll
        for (int nb = 0; nb < 4; ++nb) {
            const int p = wv * 64 + nb * 16 + (lane & 15);
            const int hh = h0 + (p >> 5), ww2 = w0 + (p & 31);
            const int o0 = ob * 16 + ((lane >> 4) << 2);
            float4v a = acc[ob][nb];
#pragma unroll
            for (int r = 0; r < 4; ++r) {
                const int o = o0 + r;
                float v = DIRECT ? (a[r] + bias[o]) : a[r];
                dbase[(((size_t)b * Oo + o) * Hh + hh) * Ww + ww2] = v;
            }
        }
}

// out = p0 + p1 + bias (memory-bound, float4, grid-stride)
__global__ __launch_bounds__(256)
void reduce2(const float4* __restrict__ p, const float* __restrict__ bias,
             float4* __restrict__ out)
{
    const int n4 = (int)(PLANE / 4);
    for (int i = blockIdx.x * 256 + threadIdx.x; i < n4; i += gridDim.x * 256) {
        float4 a = p[i];
        float4 b = p[i + n4];
        const int o = (i / 9216) & 63;
        const float bo = bias[o];
        float4 r;
        r.x = a.x + b.x + bo; r.y = a.y + b.y + bo;
        r.z = a.z + b.z + bo; r.w = a.w + b.w + bo;
        out[i] = r;
    }
}

} // namespace

extern "C" void kernel_launch(void* const* d_in, const int* in_sizes, int n_in,
                              void* d_out, int out_size, void* d_ws, size_t ws_size,
                              hipStream_t stream) {
    (void)in_sizes; (void)n_in; (void)out_size;
    const float* x    = (const float*)d_in[0];
    const float* wgt  = (const float*)d_in[1];
    const float* bias = (const float*)d_in[2];
    float* out        = (float*)d_out;

    float* pvg  = (float*)d_ws;
    float* phg  = pvg + (size_t)NPL * PVG_PLANE;
    ushort* wbf = (ushort*)(phg + (size_t)NPL * PHG_PLANE);

    prep<<<dim3(NPREF_B + NWPREP_B), dim3(64), 0, stream>>>(x, wgt, pvg, phg, wbf);

    dim3 block(NT);
    if (ws_size >= NEED_FULL) {
        float* part = (float*)d_ws + PREFIX_FLOATS + WBF_FLOATS;
        dim3 grid(Ww / TW, Hh / TH, Bb * 2);          // 2304 blocks, 8 channels each
        fova25<8, false><<<grid, block, 0, stream>>>(wbf, bias, pvg, phg, part);
        reduce2<<<dim3(2048), dim3(256), 0, stream>>>((const float4*)part, bias, (float4*)out);
    } else {
        dim3 grid(Ww / TW, Hh / TH, Bb);              // 1152 blocks, 16 channels
        fova25<16, true><<<grid, block, 0, stream>>>(wbf, bias, pvg, phg, out);
    }
}

// Round 26
// 96.458 us; speedup vs baseline: 1.5008x; 1.1073x over previous
//
#include <hip/hip_runtime.h>
#include <hip/hip_bf16.h>

typedef __attribute__((ext_vector_type(8))) short short8v;   // bf16x8 fragment
typedef __attribute__((ext_vector_type(4))) float float4v;   // fp32x4 accum
typedef unsigned short ushort;
typedef unsigned int uint;

namespace {

constexpr int Hh = 192, Ww = 192, Cc = 16, Oo = 64, Bb = 4;
constexpr int TH = 4, TW = 32, NT = 128;     // 4x32 pixel tile, 128 threads (2 waves)
constexpr int HW = Hh * Ww;                  // 36864
constexpr int NPL = Bb * Cc;                 // 64 planes
constexpr int PVG_PLANE = 236 * 198;         // col-prefix plane
constexpr int PHG_PLANE = 198 * 236;         // row-prefix plane
constexpr size_t PREFIX_FLOATS = (size_t)NPL * (PVG_PLANE + PHG_PLANE);
// prep decomposition (256-thread blocks):
constexpr int PH_ROWS = NPL * 198;           // 12672 rows, 1 wave each
constexpr int PH_B    = PH_ROWS / 4;         // 3168 blocks (4 waves/block)
constexpr int PV_B    = (NPL * 198 + 255) / 256;   // 50
constexpr int WP_B    = 65536 / 256;         // 256
constexpr int PREP_B  = PH_B + PV_B + WP_B;  // 3474

// Each feature = (vertical segment sum) + (horizontal segment sum), scaled by 1/n.
struct FD { int hasV; int vdj, vi0, vi1; int hasH; int hdi, hj0, hj1; float inv_n; };

constexpr FD FT[49] = {
    // 9 inner taps (i,j) row-major, n=1 (as V-singles)
    {1,-1,-1,-1, 0,0,0,0, 1.f}, {1, 0,-1,-1, 0,0,0,0, 1.f}, {1, 1,-1,-1, 0,0,0,0, 1.f},
    {1,-1, 0, 0, 0,0,0,0, 1.f}, {1, 0, 0, 0, 0,0,0,0, 1.f}, {1, 1, 0, 0, 0,0,0,0, 1.f},
    {1,-1, 1, 1, 0,0,0,0, 1.f}, {1, 0, 1, 1, 0,0,0,0, 1.f}, {1, 1, 1, 1, 0,0,0,0, 1.f},
    // ring5 (16)
    {1,-2,-2, 2, 1,-2,-1, 2, 1.f/9.f},
    {1,-1,-2, 2, 0,0,0,0, 0.2f},
    {1, 0,-2, 2, 0,0,0,0, 0.2f},
    {1, 1,-2, 2, 0,0,0,0, 0.2f},
    {1, 2,-2, 2, 1,-2,-2, 1, 1.f/9.f},
    {0,0,0,0, 1,-1,-2, 2, 0.2f},
    {0,0,0,0, 1,-1,-2, 2, 0.2f},
    {0,0,0,0, 1, 0,-2, 2, 0.2f},
    {0,0,0,0, 1, 0,-2, 2, 0.2f},
    {0,0,0,0, 1, 1,-2, 2, 0.2f},
    {0,0,0,0, 1, 1,-2, 2, 0.2f},
    {1,-2,-2, 2, 1, 2,-1, 2, 1.f/9.f},
    {1,-1,-2, 2, 0,0,0,0, 0.2f},
    {1, 0,-2, 2, 0,0,0,0, 0.2f},
    {1, 1,-2, 2, 0,0,0,0, 0.2f},
    {1, 2,-2, 2, 1, 2,-2, 1, 1.f/9.f},
    // ring7 (24)
    {1,-3,-3,11, 1,-3,-2,21, 1.f/39.f},
    {1,-2,-3,11, 0,0,0,0, 1.f/15.f},
    {1,-1,-3,11, 0,0,0,0, 1.f/15.f},
    {1, 0,-3,11, 0,0,0,0, 1.f/15.f},
    {1, 1,-3,11, 0,0,0,0, 1.f/15.f},
    {1, 2,-3,11, 0,0,0,0, 1.f/15.f},
    {1, 3,-3,11, 1,-3,-21, 2, 1.f/39.f},
    {0,0,0,0, 1,-2,-3,21, 0.04f},
    {0,0,0,0, 1,-2,-21,3, 0.04f},
    {0,0,0,0, 1,-1,-3,21, 0.04f},
    {0,0,0,0, 1,-1,-21,3, 0.04f},
    {0,0,0,0, 1, 0,-3,21, 0.04f},
    {0,0,0,0, 1, 0,-21,3, 0.04f},
    {0,0,0,0, 1, 1,-3,21, 0.04f},
    {0,0,0,0, 1, 1,-21,3, 0.04f},
    {0,0,0,0, 1, 2,-3,21, 0.04f},
    {0,0,0,0, 1, 2,-21,3, 0.04f},
    {1,-3,-11,3, 1, 3,-2,21, 1.f/39.f},
    {1,-2,-11,3, 0,0,0,0, 1.f/15.f},
    {1,-1,-11,3, 0,0,0,0, 1.f/15.f},
    {1, 0,-11,3, 0,0,0,0, 1.f/15.f},
    {1, 1,-11,3, 0,0,0,0, 1.f/15.f},
    {1, 2,-11,3, 0,0,0,0, 1.f/15.f},
    {1, 3,-11,3, 1, 3,-21,2, 1.f/39.f},
};

// reflect-pad(3) + clip index map; valid for u in [-21, 213]
__device__ __forceinline__ int mapIdx(int u) {
    if (u < 0) { u = -u; if (u > 3) u = 3; }
    else if (u > 191) { u = 382 - u; if (u < 188) u = 188; }
    return u;
}

// RNE fp32->bf16 bits (native; pairs fuse to v_cvt_pk_bf16_f32)
__device__ __forceinline__ ushort f2bf(float f) {
    __hip_bfloat16 h = __float2bfloat16(f);
    return __builtin_bit_cast(ushort, h);
}

// Merged prep (256-thread blocks):
//   [0, PH_B): PH rows via wave-parallel shfl scans (coalesced loads AND writes)
//   [PH_B, PH_B+PV_B): PV columns, thread-serial (coalesced across lanes)
//   [PH_B+PV_B, PREP_B): weight bf16 conversion
__global__ __launch_bounds__(256)
void prep(const float* __restrict__ x, const float* __restrict__ wgt,
          float* __restrict__ pvg, float* __restrict__ phg, ushort* __restrict__ wbf)
{
    const int bid = blockIdx.x, tid = threadIdx.x;
    if (bid < PH_B) {
        const int lane = tid & 63;
        const int row  = bid * 4 + (tid >> 6);
        const int plane = row / 198;
        const int q     = row - plane * 198;
        const float* xp = x + (size_t)plane * HW;
        const int rsrc  = mapIdx(q - 3) * Ww;
        float* ph = phg + (size_t)plane * PHG_PLANE + (size_t)q * 236;
        if (lane == 0) ph[0] = 0.f;
        float carry = 0.f;
#pragma unroll
        for (int ck = 0; ck < 4; ++ck) {
            const int idx = ck * 64 + lane;
            float v = (idx < 235) ? xp[rsrc + mapIdx(idx - 21)] : 0.f;
#pragma unroll
            for (int d = 1; d < 64; d <<= 1) {
                float t2 = __shfl_up(v, d);
                if (lane >= d) v += t2;
            }
            if (idx < 235) ph[idx + 1] = v + carry;
            carry += __shfl(v, 63);
        }
        return;
    }
    if (bid < PH_B + PV_B) {
        const int t = (bid - PH_B) * 256 + tid;
        if (t >= NPL * 198) return;
        const int plane = t / 198;
        const int q     = t - plane * 198;
        const float* xp = x + (size_t)plane * HW;
        const int wsrc = mapIdx(q - 3);
        float* pv = pvg + (size_t)plane * PVG_PLANE + q;
        float r = 0.f;
        pv[0] = 0.f;
        for (int t0 = 0; t0 < 235; t0 += 5) {
            float v0 = xp[mapIdx(t0 - 21) * Ww + wsrc];
            float v1 = xp[mapIdx(t0 - 20) * Ww + wsrc];
            float v2 = xp[mapIdx(t0 - 19) * Ww + wsrc];
            float v3 = xp[mapIdx(t0 - 18) * Ww + wsrc];
            float v4 = xp[mapIdx(t0 - 17) * Ww + wsrc];
            float* pd = pv + (size_t)(t0 + 1) * 198;
            r += v0; pd[0]   = r;
            r += v1; pd[198] = r;
            r += v2; pd[396] = r;
            r += v3; pd[594] = r;
            r += v4; pd[792] = r;
        }
        return;
    }
    {
        const int t = (bid - PH_B - PV_B) * 256 + tid;   // 65536 entries
        const int k = t & 63, o = (t >> 6) & 63, c = t >> 12;
        wbf[t] = (k < 49) ? f2bf(wgt[o * 784 + c * 49 + k]) : (ushort)0;
    }
}

// Direct 16-channel kernel (fova25 inner loop verbatim; writes out+bias).
__global__ __launch_bounds__(NT, 3)
void fova26(const ushort* __restrict__ wbf, const float* __restrict__ bias,
            const float* __restrict__ pvg, const float* __restrict__ phg,
            float* __restrict__ out)
{
    __shared__ __align__(16) ushort featB[NT][72];   // 18432 B, 144B rows (16B-aligned)
    __shared__ __align__(16) ushort wlds[64][72];    //  9216 B
    __shared__ float  pvt[27][40];                   //  4320 B
    __shared__ float  pht[10][76];                   //  3040 B  (total 35008 -> 4 blk/CU)

    const int tid  = threadIdx.x;
    const int lane = tid & 63;
    const int wv   = tid >> 6;          // wave id 0/1
    const int w0   = blockIdx.x * TW;
    const int h0   = blockIdx.y * TH;
    const int b    = blockIdx.z;
    const int ph_  = tid >> 5;          // pixel row 0..3 (tid == pixel id)
    const int pw   = tid & 31;

    float4v acc[4][4];
#pragma unroll
    for (int i = 0; i < 4; ++i)
#pragma unroll
        for (int j = 0; j < 4; ++j) acc[i][j] = (float4v)(0.f);

#pragma unroll
    for (int f = 49; f < 64; ++f) featB[tid][f] = 0;

    const float* pvsrc = pvg + (size_t)(b * Cc) * PVG_PLANE + (size_t)(h0 + 10) * 198 + w0;
    const float* phsrc = phg + (size_t)(b * Cc) * PHG_PLANE + (size_t)h0 * 236 + w0;
    const ushort* wsrc0 = wbf + tid * 32;

    // ---- prologue: stage tiles(c0) ----
    for (int idx = tid; idx < 27 * 38; idx += NT) {
        int r = idx / 38, c = idx - r * 38;
        pvt[r][c] = pvsrc[r * 198 + c];
    }
    for (int idx = tid; idx < 10 * 75; idx += NT) {
        int r = idx / 75, c = idx - r * 75;
        pht[r][c] = phsrc[r * 236 + c];
    }
    __syncthreads();

    for (int cc = 0; cc < Cc; ++cc) {
        // ---- W(c) regs: issue early ----
        short8v wreg[4];
#pragma unroll
        for (int q = 0; q < 4; ++q)
            wreg[q] = *(const short8v*)(&wsrc0[q * 8]);

        // ---- features from LDS tiles; b128 stores ----
        {
            auto FV = [&](int f) -> float {
                float s = 0.f;
                if (FT[f].hasV)
                    s += pvt[ph_ + FT[f].vi1 + 12][pw + 3 + FT[f].vdj]
                       - pvt[ph_ + FT[f].vi0 + 11][pw + 3 + FT[f].vdj];
                if (FT[f].hasH)
                    s += pht[ph_ + 3 + FT[f].hdi][pw + 21 + FT[f].hj1 + 1]
                       - pht[ph_ + 3 + FT[f].hdi][pw + 21 + FT[f].hj0];
                return s * FT[f].inv_n;
            };
            auto pk = [](float a, float bq) -> uint {
                return (uint)f2bf(a) | ((uint)f2bf(bq) << 16);
            };
            uint4* fb = reinterpret_cast<uint4*>(&featB[tid][0]);
#pragma unroll
            for (int g = 0; g < 6; ++g) {
                uint4 U;
                U.x = pk(FV(g * 8 + 0), FV(g * 8 + 1));
                U.y = pk(FV(g * 8 + 2), FV(g * 8 + 3));
                U.z = pk(FV(g * 8 + 4), FV(g * 8 + 5));
                U.w = pk(FV(g * 8 + 6), FV(g * 8 + 7));
                fb[g] = U;
            }
            featB[tid][48] = f2bf(FV(48));
        }
        // ---- wlds write ----
        {
            const int base = tid * 4;
#pragma unroll
            for (int q = 0; q < 4; ++q) {
                const int idx = base + q;
                *(short8v*)(&wlds[idx >> 3][(idx & 7) * 8]) = wreg[q];
            }
        }
        __syncthreads();   // featB/wlds ready; all tile reads done

        // ---- stage-loads(c+1): issue BEFORE MFMA ----
        float pvr[9], phr[6];
        const bool more = (cc + 1 < Cc);
        if (more) {
            const float* pvn = pvsrc + PVG_PLANE;
            const float* phn = phsrc + PHG_PLANE;
#pragma unroll
            for (int k = 0; k < 9; ++k) {
                int idx = tid + k * NT;
                if (idx < 27 * 38) pvr[k] = pvn[(idx / 38) * 198 + (idx % 38)];
            }
#pragma unroll
            for (int k = 0; k < 6; ++k) {
                int idx = tid + k * NT;
                if (idx < 10 * 75) phr[k] = phn[(idx / 75) * 236 + (idx % 75)];
            }
        }

        // ---- MFMA(c): A from wlds (b128), B from featB (b128) ----
        {
            const int olo = lane & 15, kg = lane >> 4;
#pragma unroll
            for (int kc = 0; kc < 2; ++kc) {
                const int k0 = kc * 32 + kg * 8;
                short8v afr[4];
#pragma unroll
                for (int ob = 0; ob < 4; ++ob) {
                    const int o = ob * 16 + olo;
                    afr[ob] = *(const short8v*)(&wlds[o][k0]);
                }
                short8v bfr[4];
#pragma unroll
                for (int nb = 0; nb < 4; ++nb) {
                    const int p = wv * 64 + nb * 16 + olo;
                    bfr[nb] = *(const short8v*)(&featB[p][k0]);
                }
#pragma unroll
                for (int ob = 0; ob < 4; ++ob)
#pragma unroll
                    for (int nb = 0; nb < 4; ++nb)
                        acc[ob][nb] = __builtin_amdgcn_mfma_f32_16x16x32_bf16(
                            afr[ob], bfr[nb], acc[ob][nb], 0, 0, 0);
            }
        }

        // ---- write tiles(c+1) ----
        if (more) {
#pragma unroll
            for (int k = 0; k < 9; ++k) {
                int idx = tid + k * NT;
                if (idx < 27 * 38) pvt[idx / 38][idx % 38] = pvr[k];
            }
#pragma unroll
            for (int k = 0; k < 6; ++k) {
                int idx = tid + k * NT;
                if (idx < 10 * 75) pht[idx / 75][idx % 75] = phr[k];
            }
        }
        __syncthreads();   // MFMA done; tiles(c+1) ready

        pvsrc += PVG_PLANE; phsrc += PHG_PLANE; wsrc0 += 4096;
    }

    // ---- epilogue: direct store with bias ----
#pragma unroll
    for (int ob = 0; ob < 4; ++ob)
#pragma unroll
        for (int nb = 0; nb < 4; ++nb) {
            const int p = wv * 64 + nb * 16 + (lane & 15);
            const int hh = h0 + (p >> 5), ww2 = w0 + (p & 31);
            const int o0 = ob * 16 + ((lane >> 4) << 2);
            float4v a = acc[ob][nb];
#pragma unroll
            for (int r = 0; r < 4; ++r) {
                const int o = o0 + r;
                out[(((size_t)b * Oo + o) * Hh + hh) * Ww + ww2] = a[r] + bias[o];
            }
        }
}

} // namespace

extern "C" void kernel_launch(void* const* d_in, const int* in_sizes, int n_in,
                              void* d_out, int out_size, void* d_ws, size_t ws_size,
                              hipStream_t stream) {
    (void)in_sizes; (void)n_in; (void)out_size; (void)ws_size;
    const float* x    = (const float*)d_in[0];
    const float* wgt  = (const float*)d_in[1];
    const float* bias = (const float*)d_in[2];
    float* out        = (float*)d_out;

    float* pvg  = (float*)d_ws;
    float* phg  = pvg + (size_t)NPL * PVG_PLANE;
    ushort* wbf = (ushort*)(phg + (size_t)NPL * PHG_PLANE);   // needs ~24.3 MB total

    prep<<<dim3(PREP_B), dim3(256), 0, stream>>>(x, wgt, pvg, phg, wbf);

    dim3 grid(Ww / TW, Hh / TH, Bb);   // 6 x 48 x 4 = 1152 blocks
    fova26<<<grid, dim3(NT), 0, stream>>>(wbf, bias, pvg, phg, out);
}

// Round 27
// 94.287 us; speedup vs baseline: 1.5354x; 1.0230x over previous
//
#include <hip/hip_runtime.h>
#include <hip/hip_bf16.h>

typedef __attribute__((ext_vector_type(8))) short short8v;   // bf16x8 fragment
typedef __attribute__((ext_vector_type(4))) float float4v;   // fp32x4 accum
typedef unsigned short ushort;
typedef unsigned int uint;

namespace {

constexpr int Hh = 192, Ww = 192, Cc = 16, Oo = 64, Bb = 4;
constexpr int TH = 4, TW = 32, NT = 128;     // 4x32 pixel tile, 128 threads (2 waves)
constexpr int HW = Hh * Ww;                  // 36864
constexpr int NPL = Bb * Cc;                 // 64 planes
constexpr int PVG_PLANE = 236 * 198;         // col-prefix plane
constexpr int PHG_PLANE = 198 * 236;         // row-prefix plane
// prep decomposition (256-thread blocks):
constexpr int PH_ROWS = NPL * 198;           // 12672 rows, 1 wave each
constexpr int PH_B    = PH_ROWS / 4;         // 3168 blocks (4 waves/block)
constexpr int PV_B    = (NPL * 198 + 255) / 256;   // 50
constexpr int WP_B    = 65536 / 256;         // 256
constexpr int PREP_B  = PH_B + PV_B + WP_B;  // 3474

// reflect-pad(3) + clip index map; valid for u in [-21, 213]
__device__ __forceinline__ int mapIdx(int u) {
    if (u < 0) { u = -u; if (u > 3) u = 3; }
    else if (u > 191) { u = 382 - u; if (u < 188) u = 188; }
    return u;
}

// RNE fp32->bf16 bits (native; pairs fuse to v_cvt_pk_bf16_f32)
__device__ __forceinline__ ushort f2bf(float f) {
    __hip_bfloat16 h = __float2bfloat16(f);
    return __builtin_bit_cast(ushort, h);
}

// Merged prep (256-thread blocks): PH wave-scans / PV serial / weight conversion.
__global__ __launch_bounds__(256)
void prep(const float* __restrict__ x, const float* __restrict__ wgt,
          float* __restrict__ pvg, float* __restrict__ phg, ushort* __restrict__ wbf)
{
    const int bid = blockIdx.x, tid = threadIdx.x;
    if (bid < PH_B) {
        const int lane = tid & 63;
        const int row  = bid * 4 + (tid >> 6);
        const int plane = row / 198;
        const int q     = row - plane * 198;
        const float* xp = x + (size_t)plane * HW;
        const int rsrc  = mapIdx(q - 3) * Ww;
        float* ph = phg + (size_t)plane * PHG_PLANE + (size_t)q * 236;
        if (lane == 0) ph[0] = 0.f;
        float carry = 0.f;
#pragma unroll
        for (int ck = 0; ck < 4; ++ck) {
            const int idx = ck * 64 + lane;
            float v = (idx < 235) ? xp[rsrc + mapIdx(idx - 21)] : 0.f;
#pragma unroll
            for (int d = 1; d < 64; d <<= 1) {
                float t2 = __shfl_up(v, d);
                if (lane >= d) v += t2;
            }
            if (idx < 235) ph[idx + 1] = v + carry;
            carry += __shfl(v, 63);
        }
        return;
    }
    if (bid < PH_B + PV_B) {
        const int t = (bid - PH_B) * 256 + tid;
        if (t >= NPL * 198) return;
        const int plane = t / 198;
        const int q     = t - plane * 198;
        const float* xp = x + (size_t)plane * HW;
        const int wsrc = mapIdx(q - 3);
        float* pv = pvg + (size_t)plane * PVG_PLANE + q;
        float r = 0.f;
        pv[0] = 0.f;
        for (int t0 = 0; t0 < 235; t0 += 5) {
            float v0 = xp[mapIdx(t0 - 21) * Ww + wsrc];
            float v1 = xp[mapIdx(t0 - 20) * Ww + wsrc];
            float v2 = xp[mapIdx(t0 - 19) * Ww + wsrc];
            float v3 = xp[mapIdx(t0 - 18) * Ww + wsrc];
            float v4 = xp[mapIdx(t0 - 17) * Ww + wsrc];
            float* pd = pv + (size_t)(t0 + 1) * 198;
            r += v0; pd[0]   = r;
            r += v1; pd[198] = r;
            r += v2; pd[396] = r;
            r += v3; pd[594] = r;
            r += v4; pd[792] = r;
        }
        return;
    }
    {
        const int t = (bid - PH_B - PV_B) * 256 + tid;   // 65536 entries
        const int k = t & 63, o = (t >> 6) & 63, c = t >> 12;
        wbf[t] = (k < 49) ? f2bf(wgt[o * 784 + c * 49 + k]) : (ushort)0;
    }
}

// Direct 16-channel kernel; feature phase deduped (bit-identical expressions).
__global__ __launch_bounds__(NT, 3)
void fova27(const ushort* __restrict__ wbf, const float* __restrict__ bias,
            const float* __restrict__ pvg, const float* __restrict__ phg,
            float* __restrict__ out)
{
    __shared__ __align__(16) ushort featB[NT][72];   // 18432 B, 144B rows (16B-aligned)
    __shared__ __align__(16) ushort wlds[64][72];    //  9216 B
    __shared__ float  pvt[27][40];                   //  4320 B
    __shared__ float  pht[10][76];                   //  3040 B  (total 35008 -> 4 blk/CU)

    const int tid  = threadIdx.x;
    const int lane = tid & 63;
    const int wv   = tid >> 6;          // wave id 0/1
    const int w0   = blockIdx.x * TW;
    const int h0   = blockIdx.y * TH;
    const int b    = blockIdx.z;
    const int ph_  = tid >> 5;          // pixel row 0..3 (tid == pixel id)
    const int pw   = tid & 31;

    float4v acc[4][4];
#pragma unroll
    for (int i = 0; i < 4; ++i)
#pragma unroll
        for (int j = 0; j < 4; ++j) acc[i][j] = (float4v)(0.f);

#pragma unroll
    for (int f = 49; f < 64; ++f) featB[tid][f] = 0;

    const float* pvsrc = pvg + (size_t)(b * Cc) * PVG_PLANE + (size_t)(h0 + 10) * 198 + w0;
    const float* phsrc = phg + (size_t)(b * Cc) * PHG_PLANE + (size_t)h0 * 236 + w0;
    const ushort* wsrc0 = wbf + tid * 32;

    // ---- prologue: stage tiles(c0) ----
    for (int idx = tid; idx < 27 * 38; idx += NT) {
        int r = idx / 38, c = idx - r * 38;
        pvt[r][c] = pvsrc[r * 198 + c];
    }
    for (int idx = tid; idx < 10 * 75; idx += NT) {
        int r = idx / 75, c = idx - r * 75;
        pht[r][c] = phsrc[r * 236 + c];
    }
    __syncthreads();

    for (int cc = 0; cc < Cc; ++cc) {
        // ---- W(c) regs: issue early ----
        short8v wreg[4];
#pragma unroll
        for (int q = 0; q < 4; ++q)
            wreg[q] = *(const short8v*)(&wsrc0[q * 8]);

        // ---- features (deduped; expressions bit-identical to fova26's FV) ----
        {
            auto pk = [](float a, float bq) -> uint {
                return (uint)f2bf(a) | ((uint)f2bf(bq) << 16);
            };
            const float n9 = 1.f / 9.f, n15 = 1.f / 15.f, n39 = 1.f / 39.f;
            const int CB = pw + 21;
            uint4* fb = reinterpret_cast<uint4*>(&featB[tid][0]);
            uint4 U;

            // --- inner 3x3: 12 loads -> 9 diffs ---
            float i00, i10, i20, i01, i11, i21, i02, i12, i22;
            {
                float m2, m1, z0, p1;
                m2 = pvt[ph_ + 10][pw + 2]; m1 = pvt[ph_ + 11][pw + 2];
                z0 = pvt[ph_ + 12][pw + 2]; p1 = pvt[ph_ + 13][pw + 2];
                i00 = m1 - m2; i01 = z0 - m1; i02 = p1 - z0;
                m2 = pvt[ph_ + 10][pw + 3]; m1 = pvt[ph_ + 11][pw + 3];
                z0 = pvt[ph_ + 12][pw + 3]; p1 = pvt[ph_ + 13][pw + 3];
                i10 = m1 - m2; i11 = z0 - m1; i12 = p1 - z0;
                m2 = pvt[ph_ + 10][pw + 4]; m1 = pvt[ph_ + 11][pw + 4];
                z0 = pvt[ph_ + 12][pw + 4]; p1 = pvt[ph_ + 13][pw + 4];
                i20 = m1 - m2; i21 = z0 - m1; i22 = p1 - z0;
            }
            U.x = pk(i00, i10); U.y = pk(i20, i01);
            U.z = pk(i11, i21); U.w = pk(i02, i12);
            fb[0] = U;

            // --- ring5 shared V diffs (cols pw+1..pw+5) ---
            float r50 = pvt[ph_ + 14][pw + 1] - pvt[ph_ + 9][pw + 1];
            float r51 = pvt[ph_ + 14][pw + 2] - pvt[ph_ + 9][pw + 2];
            float r52 = pvt[ph_ + 14][pw + 3] - pvt[ph_ + 9][pw + 3];
            float r53 = pvt[ph_ + 14][pw + 4] - pvt[ph_ + 9][pw + 4];
            float r54 = pvt[ph_ + 14][pw + 5] - pvt[ph_ + 9][pw + 5];
            const float* hm2 = &pht[ph_ + 1][0];   // hdi=-2
            const float* hp2 = &pht[ph_ + 5][0];   // hdi=+2
            float f9  = (r50 + (hm2[CB + 3] - hm2[CB - 1])) * n9;
            float f13 = (r54 + (hm2[CB + 2] - hm2[CB - 2])) * n9;
            float s14 = (pht[ph_ + 2][CB + 3] - pht[ph_ + 2][CB - 2]) * 0.2f;
            U.x = pk(i22, f9); U.y = pk(r51 * 0.2f, r52 * 0.2f);
            U.z = pk(r53 * 0.2f, f13); U.w = pk(s14, s14);
            fb[1] = U;

            float s16 = (pht[ph_ + 3][CB + 3] - pht[ph_ + 3][CB - 2]) * 0.2f;
            float s18 = (pht[ph_ + 4][CB + 3] - pht[ph_ + 4][CB - 2]) * 0.2f;
            float f20 = (r50 + (hp2[CB + 3] - hp2[CB - 1])) * n9;
            U.x = pk(s16, s16); U.y = pk(s18, s18);
            U.z = pk(f20, r51 * 0.2f); U.w = pk(r52 * 0.2f, r53 * 0.2f);
            fb[2] = U;

            // --- ring7 down (rows -3): V = pvt[+23]-pvt[+8] ---
            const float* hm3 = &pht[ph_ + 0][0];
            const float* hp3 = &pht[ph_ + 6][0];
            float f24 = (r54 + (hp2[CB + 2] - hp2[CB - 2])) * n9;
            float d0 = pvt[ph_ + 23][pw + 0] - pvt[ph_ + 8][pw + 0];
            float d1 = pvt[ph_ + 23][pw + 1] - pvt[ph_ + 8][pw + 1];
            float d2 = pvt[ph_ + 23][pw + 2] - pvt[ph_ + 8][pw + 2];
            float d3 = pvt[ph_ + 23][pw + 3] - pvt[ph_ + 8][pw + 3];
            float d4 = pvt[ph_ + 23][pw + 4] - pvt[ph_ + 8][pw + 4];
            float d5 = pvt[ph_ + 23][pw + 5] - pvt[ph_ + 8][pw + 5];
            float d6 = pvt[ph_ + 23][pw + 6] - pvt[ph_ + 8][pw + 6];
            float f25 = (d0 + (hm3[CB + 22] - hm3[CB - 2])) * n39;
            float f31 = (d6 + (hm3[CB + 3] - hm3[CB - 21])) * n39;
            U.x = pk(f24, f25); U.y = pk(d1 * n15, d2 * n15);
            U.z = pk(d3 * n15, d4 * n15); U.w = pk(d5 * n15, f31);
            fb[3] = U;

            // --- H-only rows (0.04): rows ph_+1..ph_+4 ---
            {
                const float* r2 = &pht[ph_ + 2][0];
                const float* r3 = &pht[ph_ + 3][0];
                const float* r4 = &pht[ph_ + 4][0];
                float f32 = (hm2[CB + 22] - hm2[CB - 3]) * 0.04f;
                float f33 = (hm2[CB + 4]  - hm2[CB - 21]) * 0.04f;
                float f34 = (r2[CB + 22] - r2[CB - 3]) * 0.04f;
                float f35 = (r2[CB + 4]  - r2[CB - 21]) * 0.04f;
                float f36 = (r3[CB + 22] - r3[CB - 3]) * 0.04f;
                float f37 = (r3[CB + 4]  - r3[CB - 21]) * 0.04f;
                float f38 = (r4[CB + 22] - r4[CB - 3]) * 0.04f;
                float f39 = (r4[CB + 4]  - r4[CB - 21]) * 0.04f;
                U.x = pk(f32, f33); U.y = pk(f34, f35);
                U.z = pk(f36, f37); U.w = pk(f38, f39);
                fb[4] = U;
            }

            // --- ring7 up (rows +3): V = pvt[+15]-pvt[+0] ---
            {
                float f40 = (hp2[CB + 22] - hp2[CB - 3]) * 0.04f;
                float f41 = (hp2[CB + 4]  - hp2[CB - 21]) * 0.04f;
                float u0 = pvt[ph_ + 15][pw + 0] - pvt[ph_ + 0][pw + 0];
                float u1 = pvt[ph_ + 15][pw + 1] - pvt[ph_ + 0][pw + 1];
                float u2 = pvt[ph_ + 15][pw + 2] - pvt[ph_ + 0][pw + 2];
                float u3 = pvt[ph_ + 15][pw + 3] - pvt[ph_ + 0][pw + 3];
                float u4 = pvt[ph_ + 15][pw + 4] - pvt[ph_ + 0][pw + 4];
                float u5 = pvt[ph_ + 15][pw + 5] - pvt[ph_ + 0][pw + 5];
                float u6 = pvt[ph_ + 15][pw + 6] - pvt[ph_ + 0][pw + 6];
                float f42 = (u0 + (hp3[CB + 22] - hp3[CB - 2])) * n39;
                float f48 = (u6 + (hp3[CB + 3]  - hp3[CB - 21])) * n39;
                U.x = pk(f40, f41); U.y = pk(f42, u1 * n15);
                U.z = pk(u2 * n15, u3 * n15); U.w = pk(u4 * n15, u5 * n15);
                fb[5] = U;
                featB[tid][48] = f2bf(f48);
            }
        }
        // ---- wlds write ----
        {
            const int base = tid * 4;
#pragma unroll
            for (int q = 0; q < 4; ++q) {
                const int idx = base + q;
                *(short8v*)(&wlds[idx >> 3][(idx & 7) * 8]) = wreg[q];
            }
        }
        __syncthreads();   // featB/wlds ready; all tile reads done

        // ---- stage-loads(c+1): issue BEFORE MFMA ----
        float pvr[9], phr[6];
        const bool more = (cc + 1 < Cc);
        if (more) {
            const float* pvn = pvsrc + PVG_PLANE;
            const float* phn = phsrc + PHG_PLANE;
#pragma unroll
            for (int k = 0; k < 9; ++k) {
                int idx = tid + k * NT;
                if (idx < 27 * 38) pvr[k] = pvn[(idx / 38) * 198 + (idx % 38)];
            }
#pragma unroll
            for (int k = 0; k < 6; ++k) {
                int idx = tid + k * NT;
                if (idx < 10 * 75) phr[k] = phn[(idx / 75) * 236 + (idx % 75)];
            }
        }

        // ---- MFMA(c): A from wlds (b128), B from featB (b128) ----
        {
            const int olo = lane & 15, kg = lane >> 4;
#pragma unroll
            for (int kc = 0; kc < 2; ++kc) {
                const int k0 = kc * 32 + kg * 8;
                short8v afr[4];
#pragma unroll
                for (int ob = 0; ob < 4; ++ob) {
                    const int o = ob * 16 + olo;
                    afr[ob] = *(const short8v*)(&wlds[o][k0]);
                }
                short8v bfr[4];
#pragma unroll
                for (int nb = 0; nb < 4; ++nb) {
                    const int p = wv * 64 + nb * 16 + olo;
                    bfr[nb] = *(const short8v*)(&featB[p][k0]);
                }
#pragma unroll
                for (int ob = 0; ob < 4; ++ob)
#pragma unroll
                    for (int nb = 0; nb < 4; ++nb)
                        acc[ob][nb] = __builtin_amdgcn_mfma_f32_16x16x32_bf16(
                            afr[ob], bfr[nb], acc[ob][nb], 0, 0, 0);
            }
        }

        // ---- write tiles(c+1) ----
        if (more) {
#pragma unroll
            for (int k = 0; k < 9; ++k) {
                int idx = tid + k * NT;
                if (idx < 27 * 38) pvt[idx / 38][idx % 38] = pvr[k];
            }
#pragma unroll
            for (int k = 0; k < 6; ++k) {
                int idx = tid + k * NT;
                if (idx < 10 * 75) pht[idx / 75][idx % 75] = phr[k];
            }
        }
        __syncthreads();   // MFMA done; tiles(c+1) ready

        pvsrc += PVG_PLANE; phsrc += PHG_PLANE; wsrc0 += 4096;
    }

    // ---- epilogue: direct store with bias ----
#pragma unroll
    for (int ob = 0; ob < 4; ++ob)
#pragma unroll
        for (int nb = 0; nb < 4; ++nb) {
            const int p = wv * 64 + nb * 16 + (lane & 15);
            const int hh = h0 + (p >> 5), ww2 = w0 + (p & 31);
            const int o0 = ob * 16 + ((lane >> 4) << 2);
            float4v a = acc[ob][nb];
#pragma unroll
            for (int r = 0; r < 4; ++r) {
                const int o = o0 + r;
                out[(((size_t)b * Oo + o) * Hh + hh) * Ww + ww2] = a[r] + bias[o];
            }
        }
}

} // namespace

extern "C" void kernel_launch(void* const* d_in, const int* in_sizes, int n_in,
                              void* d_out, int out_size, void* d_ws, size_t ws_size,
                              hipStream_t stream) {
    (void)in_sizes; (void)n_in; (void)out_size; (void)ws_size;
    const float* x    = (const float*)d_in[0];
    const float* wgt  = (const float*)d_in[1];
    const float* bias = (const float*)d_in[2];
    float* out        = (float*)d_out;

    float* pvg  = (float*)d_ws;
    float* phg  = pvg + (size_t)NPL * PVG_PLANE;
    ushort* wbf = (ushort*)(phg + (size_t)NPL * PHG_PLANE);   // needs ~24.3 MB total

    prep<<<dim3(PREP_B), dim3(256), 0, stream>>>(x, wgt, pvg, phg, wbf);

    dim3 grid(Ww / TW, Hh / TH, Bb);   // 6 x 48 x 4 = 1152 blocks
    fova27<<<grid, dim3(NT), 0, stream>>>(wbf, bias, pvg, phg, out);
}